// Round 2
// baseline (503.684 us; speedup 1.0000x reference)
//
#include <hip/hip_runtime.h>

// Fully-fused undecimated starlet, 4 scales in ONE kernel.
// Tile 64x64 output, halo 30 (= 2+4+8+16), staged region 124x124 in LDS.
// Per scale: horizontal 5-tap dilated pass A->B, vertical pass B->(coeff, A in-place).
// Symmetric mirroring once at staging: symmetric filter + half-sample-symmetric
// extension => extension property propagates through every scale, matching the
// reference's per-scale jnp.pad(mode='symmetric').

#define IMG   1024
#define NB    16
#define TILE  64
#define HALO  30
#define SPAN  124                 // TILE + 2*HALO
#define NSTAGE (SPAN * SPAN)      // 15376 floats = 61.5 KB per buffer
#define NT    1024                // threads per block

__device__ __forceinline__ int mirror_idx(int g) {
    // jnp.pad mode='symmetric'; HALO < IMG so a single reflection suffices
    g = (g < 0) ? (-1 - g) : g;
    g = (g >= IMG) ? (2 * IMG - 1 - g) : g;
    return g;
}

template <int D, int MIN, int MOUT>
__device__ __forceinline__ void scale_step(float* A, float* B,
                                           float* __restrict__ coeff, float inv,
                                           int tid, size_t img_off, int ty0, int tx0)
{
    constexpr int SIN  = TILE + 2 * MIN;   // valid rows of A entering this scale
    constexpr int SOUT = TILE + 2 * MOUT;  // valid span leaving this scale
    constexpr int Y0   = HALO - MIN;
    constexpr int X0   = HALO - MOUT;

    // horizontal dilated 5-tap: A -> B over [Y0,Y0+SIN) x [X0,X0+SOUT)
    for (int i = tid; i < SIN * SOUT; i += NT) {
        const int y = Y0 + i / SOUT;
        const int x = X0 + i % SOUT;
        const float* a = A + y * SPAN + x;
        B[y * SPAN + x] = 0.375f  * a[0]
                        + 0.25f   * (a[-D]     + a[D])
                        + 0.0625f * (a[-2 * D] + a[2 * D]);
    }
    __syncthreads();

    // vertical dilated 5-tap: B -> new_low; coeff = (low - new_low)*inv in the
    // central 64x64; A updated in place (each element read+written by its own thread)
    for (int i = tid; i < SOUT * SOUT; i += NT) {
        const int y = X0 + i / SOUT;
        const int x = X0 + i % SOUT;
        const float* b = B + y * SPAN + x;
        const float nl = 0.375f  * b[0]
                       + 0.25f   * (b[-D * SPAN]     + b[D * SPAN])
                       + 0.0625f * (b[-2 * D * SPAN] + b[2 * D * SPAN]);
        float* ap = A + y * SPAN + x;
        const float lo = *ap;
        *ap = nl;
        const int oy = y - HALO, ox = x - HALO;
        if ((unsigned)oy < TILE && (unsigned)ox < TILE) {
            coeff[img_off + (size_t)(ty0 + oy) * IMG + (tx0 + ox)] = (lo - nl) * inv;
        }
    }
    __syncthreads();
}

__global__ __launch_bounds__(NT, 1)
void starlet_fused_kernel(const float* __restrict__ img,
                          const float* __restrict__ norms,
                          float* __restrict__ out)
{
    __shared__ float A[NSTAGE];
    __shared__ float B[NSTAGE];

    const int tid = threadIdx.x;
    const int tx0 = blockIdx.x * TILE;
    const int ty0 = blockIdx.y * TILE;
    const size_t img_off = (size_t)blockIdx.z * (size_t)(IMG * IMG);

    // ---- stage 124x124 mirrored region: batch loads into registers first
    // (all 16 loads in flight -> single vmcnt drain), then dump to LDS ----
    float r[16];
#pragma unroll
    for (int k = 0; k < 16; ++k) {
        const int i = tid + k * NT;
        if (i < NSTAGE) {
            const int ry = i / SPAN;
            const int rx = i - ry * SPAN;
            const int gy = mirror_idx(ty0 - HALO + ry);
            const int gx = mirror_idx(tx0 - HALO + rx);
            r[k] = img[img_off + (size_t)gy * IMG + gx];
        }
    }
#pragma unroll
    for (int k = 0; k < 16; ++k) {
        const int i = tid + k * NT;
        if (i < NSTAGE) A[i] = r[k];
    }
    __syncthreads();

    const size_t plane = (size_t)NB * IMG * IMG;
    const float inv0 = 1.0f / norms[0];
    const float inv1 = 1.0f / norms[1];
    const float inv2 = 1.0f / norms[2];
    const float inv3 = 1.0f / norms[3];

    scale_step<1, 30, 28>(A, B, out,             inv0, tid, img_off, ty0, tx0);
    scale_step<2, 28, 24>(A, B, out + plane,     inv1, tid, img_off, ty0, tx0);
    scale_step<4, 24, 16>(A, B, out + 2 * plane, inv2, tid, img_off, ty0, tx0);
    scale_step<8, 16,  0>(A, B, out + 3 * plane, inv3, tid, img_off, ty0, tx0);
}

extern "C" void kernel_launch(void* const* d_in, const int* in_sizes, int n_in,
                              void* d_out, int out_size, void* d_ws, size_t ws_size,
                              hipStream_t stream) {
    const float* image = (const float*)d_in[0];
    const float* norms = (const float*)d_in[1];
    float* out = (float*)d_out;

    dim3 grid(IMG / TILE, IMG / TILE, NB);
    dim3 block(NT);
    starlet_fused_kernel<<<grid, block, 0, stream>>>(image, norms, out);
}